// Round 3
// baseline (142.123 us; speedup 1.0000x reference)
//
#include <hip/hip_runtime.h>

#define B_     128
#define S_     256
#define MW_    21
#define VOCAB_ 100
#define EC_    50
#define EW_    256
#define KW_    5
#define T_     17              // MW - K + 1
#define NW_    (B_ * S_)       // 32768 words
#define GROWS  (VOCAB_ * KW_)  // 500
#define WPB    128             // words per mega block
#define P1B    200             // prep part-1 blocks: 50 v-pairs x 4 o-tiles
#define GST    72              // g_s row stride in halves (144 B = 4.5 bank-quads
                               //  -> row r starts at bank-quad r%8: decorrelates
                               //  the 8 wq-groups' same-column reads)

typedef _Float16 f16x8 __attribute__((ext_vector_type(8)));
typedef float    f32x4 __attribute__((ext_vector_type(4)));

// ---------------- kernel 1: prep (unchanged from R1 — saved ~4 us vs R0)
__global__ __launch_bounds__(256) void k_prep(const float* __restrict__ emb,
                                              const float* __restrict__ cw,
                                              const float* __restrict__ Wp,
                                              const float* __restrict__ Wg,
                                              _Float16* __restrict__ g,
                                              _Float16* __restrict__ wpf,
                                              _Float16* __restrict__ wgf) {
  const int bi = blockIdx.x;
  if (bi < P1B) {
    __shared__ float ls[64 * 250];          // one o-tile of cw, natural layout
    const int vp = bi >> 2, ot = bi & 3;
    const int o0 = ot * 64;
    const int tid = threadIdx.x;
    const float4* __restrict__ cw4 = (const float4*)cw + ot * 4000;  // tile base
#pragma unroll 4
    for (int idx4 = tid; idx4 < 4000; idx4 += 256)
      *(float4*)&ls[idx4 * 4] = cw4[idx4];
    __syncthreads();

    const int l = tid & 63, wv = tid >> 6;   // lane = o_local, wave = k (0..3)
#pragma unroll
    for (int vv = 0; vv < 2; ++vv) {
      const int v = vp * 2 + vv;
      const float* __restrict__ er = emb + v * EC_;   // uniform -> s_load
      float acc = 0.f;
#pragma unroll
      for (int i = 0; i < EC_; ++i)
        acc += er[i] * ls[l * 250 + i * KW_ + wv];
      g[(v * KW_ + wv) * EW_ + o0 + l] = (_Float16)acc;
      if (wv == 0) {                          // wave 0 also covers k = 4
        float a4 = 0.f;
#pragma unroll
        for (int i = 0; i < EC_; ++i)
          a4 += er[i] * ls[l * 250 + i * KW_ + 4];
        g[(v * KW_ + 4) * EW_ + o0 + l] = (_Float16)a4;
      }
    }
  } else {
    const int fl  = (bi - P1B) * 256 + threadIdx.x;  // 0..8191 lane-frags
    const int nt  = fl >> 9;
    const int rem = fl & 511;
    const int ks  = rem >> 6;
    const int l   = rem & 63;
    const int n   = nt * 16 + (l & 15);
    const int kc  = ks * 32 + (l >> 4) * 8;
    const int src = n * EW_ + kc;
    const float4 p0 = *(const float4*)&Wp[src], p1 = *(const float4*)&Wp[src + 4];
    const float4 q0 = *(const float4*)&Wg[src], q1 = *(const float4*)&Wg[src + 4];
    f16x8 hp = {(_Float16)p0.x, (_Float16)p0.y, (_Float16)p0.z, (_Float16)p0.w,
                (_Float16)p1.x, (_Float16)p1.y, (_Float16)p1.z, (_Float16)p1.w};
    f16x8 hg = {(_Float16)q0.x, (_Float16)q0.y, (_Float16)q0.z, (_Float16)q0.w,
                (_Float16)q1.x, (_Float16)q1.y, (_Float16)q1.z, (_Float16)q1.w};
    *(f16x8*)&wpf[fl * 8] = hp;
    *(f16x8*)&wgf[fl * 8] = hg;
  }
}

// ---------------- kernel 2: mega — conv+relu+maxpool (A) + dual-GEMM highway (B)
// R3: (a) __launch_bounds__(1024) with NO min-waves arg — R2's (1024,4) made the
//   backend clamp to 64 VGPRs -> scratch spills (FETCH +11.6MB, WRITE +24.6MB).
//   Flat-workgroup-size 1024 alone caps at 128 VGPR, enough for ~116.
// (b) g_s row stride 64 -> GST=72 halves (144 B). With 128 B stride every row
//   started at bank 0, so the 8 wq-groups' same-octet reads of 8 random rows hit
//   one bank-quad (8-way, 4.12M conflict cyc ~ 6.7 us/CU). 144 B stride puts row
//   r at quad r%8 -> multiplicity ~2 (free per m136). Additivity base[c]+k*GST
//   and same-row broadcasts preserved. LDS = 65536 + 72000 = 137536 B, still
//   1 block/CU, 16 waves (4/SIMD saturate the LDS port ~ the 27us b128 floor).
__global__ __launch_bounds__(1024) void k_mega(const int* __restrict__ idx,
                                               const _Float16* __restrict__ g,
                                               const float* __restrict__ cb,
                                               const _Float16* __restrict__ wpf,
                                               const _Float16* __restrict__ wgf,
                                               const float* __restrict__ bp,
                                               const float* __restrict__ bg,
                                               float* __restrict__ out) {
  __shared__ __align__(16) _Float16 lds[32768 + GROWS * GST];
  _Float16* y_s = lds;            // 32768 halves: (frag*64 + (lane_t^og)) * 8 + j
  _Float16* g_s = lds + 32768;    // [500][GST], data in first 64 halves of each row

  const int tid  = threadIdx.x;
  const int wave = tid >> 6, lane = tid & 63;
  const int m0 = blockIdx.x * WPB;
  const int wq = lane >> 3, og = lane & 7;   // 8 words x 8 channel-octets per wave

  // initial stage: chunk 0
#pragma unroll
  for (int i = 0; i < 4; ++i) {
    const int c = tid + i * 1024;
    if (c < GROWS * 8) {
      const int row = c >> 3, cc = c & 7;
      *(f16x8*)&g_s[row * GST + cc * 8] = *(const f16x8*)&g[row * EW_ + cc * 8];
    }
  }
  __syncthreads();

  // per-word constants, hoisted across chunks (base is chunk-invariant)
  const int wl = wave * 8 + wq;              // word 0..127
  const int* __restrict__ ipr = idx + (m0 + wl) * MW_;
  int base[MW_];
#pragma unroll
  for (int c = 0; c < MW_; ++c)
    base[c] = ipr[c] * (KW_ * GST) + og * 8;
  const int mt_a   = wl >> 4;
  const int lt_lo  = wl & 15;
  const int ks_hi  = og >> 2;
  const int lane_hi = (og & 3) << 4;
  const int lt = (lt_lo | lane_hi) ^ og;     // swizzled granule low-6

  f16x8 pre[4];
#pragma unroll
  for (int chunk = 0; chunk < 4; ++chunk) {
    const int oc0 = chunk * 64;
    // issue next chunk's loads into registers (waited only at the ds_write below)
    if (chunk < 3) {
#pragma unroll
      for (int i = 0; i < 4; ++i) {
        const int c = tid + i * 1024;
        if (c < GROWS * 8) {
          const int row = c >> 3, cc = c & 7;
          pre[i] = *(const f16x8*)&g[row * EW_ + oc0 + 64 + cc * 8];
        }
      }
    }

    f16x8 bias;
#pragma unroll
    for (int j = 0; j < 8; ++j) bias[j] = (_Float16)cb[oc0 + og * 8 + j];

    const _Float16 NEG = (_Float16)(-60000.0f);
    f16x8 mx = {NEG, NEG, NEG, NEG, NEG, NEG, NEG, NEG};
#pragma unroll
    for (int t = 0; t < T_; ++t) {
      f16x8 s = *(const f16x8*)&g_s[base[t]];              // k = 0
#pragma unroll
      for (int k = 1; k < KW_; ++k)
        s += *(const f16x8*)&g_s[base[t + k] + k * GST];   // v_pk_add_f16
      mx = __builtin_elementwise_max(mx, s);               // v_pk_max_f16
    }
    // relu(bias + max_t s) == max_t relu(bias + s)
    const f16x8 zero8 = {0, 0, 0, 0, 0, 0, 0, 0};
    mx = __builtin_elementwise_max(mx + bias, zero8);

    *(f16x8*)&y_s[((mt_a * 8 + (chunk * 2 + ks_hi)) * 64 + lt) * 8] = mx;

    __syncthreads();  // gather(c)+y-writes complete; g_s free
    if (chunk < 3) {
#pragma unroll
      for (int i = 0; i < 4; ++i) {
        const int c = tid + i * 1024;
        if (c < GROWS * 8) {
          const int row = c >> 3, cc = c & 7;
          *(f16x8*)&g_s[row * GST + cc * 8] = pre[i];
        }
      }
      __syncthreads();
    }
  }

  // ======== phase B: dual GEMM + highway — B streamed from L2, no barriers ========
  // 16 waves: wave = (mt 0..7) x (nh 0..1); each wave: 16 rows x 128 cols.
  const int mtp = wave >> 1, nh = wave & 1;
  const int quad = lane >> 4, r16 = lane & 15;

  f16x8 a[8];
#pragma unroll
  for (int ks = 0; ks < 8; ++ks) {
    const int key = ((ks & 1) << 2) | quad;                // == writer og
    a[ks] = *(const f16x8*)&y_s[((mtp * 8 + ks) * 64 + (lane ^ key)) * 8];
  }

  const f32x4 zero = {0.f, 0.f, 0.f, 0.f};
#pragma unroll
  for (int h = 0; h < 2; ++h) {   // n-half: cols h*128 .. h*128+127
    f32x4 accp[4], accg[4];
#pragma unroll
    for (int nf = 0; nf < 4; ++nf) { accp[nf] = zero; accg[nf] = zero; }

#pragma unroll
    for (int nf = 0; nf < 4; ++nf) {
      const int nt = h * 8 + nh * 4 + nf;
#pragma unroll
      for (int ks = 0; ks < 8; ++ks) {
        const int off = ((nt * 8 + ks) * 64 + lane) * 8;
        const f16x8 bpv = *(const f16x8*)&wpf[off];
        const f16x8 bgv = *(const f16x8*)&wgf[off];
        accp[nf] = __builtin_amdgcn_mfma_f32_16x16x32_f16(a[ks], bpv, accp[nf], 0, 0, 0);
        accg[nf] = __builtin_amdgcn_mfma_f32_16x16x32_f16(a[ks], bgv, accg[nf], 0, 0, 0);
      }
    }

    // epilogue for this n-half
#pragma unroll
    for (int nf = 0; nf < 4; ++nf) {
      const int n = h * 128 + nh * 64 + nf * 16 + r16;
      const float bpn = bp[n];
      const float bgn = bg[n];
      const int ks_e = n >> 5;
      const int lane_e = ((n >> 3) & 3) << 4;
      const int og_e = (n >> 3) & 7;
      const int je = n & 7;
#pragma unroll
      for (int reg = 0; reg < 4; ++reg) {
        const int m = mtp * 16 + quad * 4 + reg;
        float p = fmaxf(accp[nf][reg] + bpn, 0.f);
        const float gz = accg[nf][reg] + bgn;
        const float gate = 1.f / (1.f + __expf(-gz));
        const float yv =
            (float)y_s[((mtp * 8 + ks_e) * 64 + (((m & 15) | lane_e) ^ og_e)) * 8 + je];
        out[(m0 + m) * EW_ + n] = gate * p + (1.f - gate) * yv;
      }
    }
  }
}

extern "C" void kernel_launch(void* const* d_in, const int* in_sizes, int n_in,
                              void* d_out, int out_size, void* d_ws, size_t ws_size,
                              hipStream_t stream) {
  (void)in_sizes; (void)n_in; (void)out_size; (void)ws_size;
  const int*   idx = (const int*)d_in[0];
  const float* emb = (const float*)d_in[1];
  const float* cw  = (const float*)d_in[2];
  const float* cb  = (const float*)d_in[3];
  const float* wp  = (const float*)d_in[4];
  const float* bpp = (const float*)d_in[5];
  const float* wgt = (const float*)d_in[6];
  const float* bgg = (const float*)d_in[7];
  float* out = (float*)d_out;
  _Float16* g_ws = (_Float16*)d_ws;            // 500*256 fp16
  _Float16* wp_f = g_ws + GROWS * EW_;         // 65536 halves, frag order
  _Float16* wg_f = wp_f + EW_ * EW_;           // 65536 halves, frag order

  k_prep<<<P1B + 32, 256, 0, stream>>>(emb, cw, wp, wgt, g_ws, wp_f, wg_f);
  k_mega<<<NW_ / WPB, 1024, 0, stream>>>(idx, g_ws, cb, wp_f, wg_f, bpp, bgg, out);
}

// Round 4
// 135.812 us; speedup vs baseline: 1.0465x; 1.0465x over previous
//
#include <hip/hip_runtime.h>

#define B_     128
#define S_     256
#define MW_    21
#define VOCAB_ 100
#define EC_    50
#define EW_    256
#define KW_    5
#define T_     17              // MW - K + 1
#define NW_    (B_ * S_)       // 32768 words
#define GROWS  (VOCAB_ * KW_)  // 500
#define WPB    128             // words per mega block
#define P1B    200             // prep part-1 blocks: 50 v-pairs x 4 o-tiles

typedef _Float16 f16x8 __attribute__((ext_vector_type(8)));
typedef float    f32x4 __attribute__((ext_vector_type(4)));

// ---------------- kernel 1: prep (unchanged from R1)
__global__ __launch_bounds__(256) void k_prep(const float* __restrict__ emb,
                                              const float* __restrict__ cw,
                                              const float* __restrict__ Wp,
                                              const float* __restrict__ Wg,
                                              _Float16* __restrict__ g,
                                              _Float16* __restrict__ wpf,
                                              _Float16* __restrict__ wgf) {
  const int bi = blockIdx.x;
  if (bi < P1B) {
    __shared__ float ls[64 * 250];          // one o-tile of cw, natural layout
    const int vp = bi >> 2, ot = bi & 3;
    const int o0 = ot * 64;
    const int tid = threadIdx.x;
    const float4* __restrict__ cw4 = (const float4*)cw + ot * 4000;  // tile base
#pragma unroll 4
    for (int idx4 = tid; idx4 < 4000; idx4 += 256)
      *(float4*)&ls[idx4 * 4] = cw4[idx4];
    __syncthreads();

    const int l = tid & 63, wv = tid >> 6;   // lane = o_local, wave = k (0..3)
#pragma unroll
    for (int vv = 0; vv < 2; ++vv) {
      const int v = vp * 2 + vv;
      const float* __restrict__ er = emb + v * EC_;   // uniform -> s_load
      float acc = 0.f;
#pragma unroll
      for (int i = 0; i < EC_; ++i)
        acc += er[i] * ls[l * 250 + i * KW_ + wv];
      g[(v * KW_ + wv) * EW_ + o0 + l] = (_Float16)acc;
      if (wv == 0) {                          // wave 0 also covers k = 4
        float a4 = 0.f;
#pragma unroll
        for (int i = 0; i < EC_; ++i)
          a4 += er[i] * ls[l * 250 + i * KW_ + 4];
        g[(v * KW_ + 4) * EW_ + o0 + l] = (_Float16)a4;
      }
    }
  } else {
    const int fl  = (bi - P1B) * 256 + threadIdx.x;  // 0..8191 lane-frags
    const int nt  = fl >> 9;
    const int rem = fl & 511;
    const int ks  = rem >> 6;
    const int l   = rem & 63;
    const int n   = nt * 16 + (l & 15);
    const int kc  = ks * 32 + (l >> 4) * 8;
    const int src = n * EW_ + kc;
    const float4 p0 = *(const float4*)&Wp[src], p1 = *(const float4*)&Wp[src + 4];
    const float4 q0 = *(const float4*)&Wg[src], q1 = *(const float4*)&Wg[src + 4];
    f16x8 hp = {(_Float16)p0.x, (_Float16)p0.y, (_Float16)p0.z, (_Float16)p0.w,
                (_Float16)p1.x, (_Float16)p1.y, (_Float16)p1.z, (_Float16)p1.w};
    f16x8 hg = {(_Float16)q0.x, (_Float16)q0.y, (_Float16)q0.z, (_Float16)q0.w,
                (_Float16)q1.x, (_Float16)q1.y, (_Float16)q1.z, (_Float16)q1.w};
    *(f16x8*)&wpf[fl * 8] = hp;
    *(f16x8*)&wgf[fl * 8] = hg;
  }
}

// ---------------- kernel 2: mega — conv+relu+maxpool (A) + dual-GEMM highway (B)
// R4: isolate the 16-wave occupancy experiment with a CLEAN compile.
//  - R2/R3 both spilled: backend occupancy heuristic chose 64 VGPRs (8 waves/EU
//    target) regardless of __launch_bounds__, scratch-spilling base[]/pre[]
//    (FETCH +12MB, WRITE +25MB). Fix: amdgpu_waves_per_eu(4,4) — occupancy IS
//    4/EU (1 block, 129.5KB LDS), pinning max=4 gives the allocator the full
//    512/4 = 128 VGPR budget and removes the incentive to spill.
//  - g_s: PLAIN stride-64. GST=72 DOUBLED conflicts (4.12M->8.0M): b128 is
//    served in 16-lane phases = 2 full 128B-aligned rows = 2 accesses/bank =
//    free; misaligned 144B rows create 3/1-way imbalance. Plain is optimal.
//  - Phase A structure as R3: no it-loop (16 waves x 8 words), base[21]+idx
//    hoisted across chunks.
__global__ __attribute__((amdgpu_flat_work_group_size(1024, 1024),
                          amdgpu_waves_per_eu(4, 4)))
void k_mega(const int* __restrict__ idx,
            const _Float16* __restrict__ g,
            const float* __restrict__ cb,
            const _Float16* __restrict__ wpf,
            const _Float16* __restrict__ wgf,
            const float* __restrict__ bp,
            const float* __restrict__ bg,
            float* __restrict__ out) {
  __shared__ __align__(16) _Float16 lds[32768 + GROWS * 64];
  _Float16* y_s = lds;            // 32768 halves: (frag*64 + (lane_t^og)) * 8 + j
  _Float16* g_s = lds + 32768;    // [500][64] plain

  const int tid  = threadIdx.x;
  const int wave = tid >> 6, lane = tid & 63;
  const int m0 = blockIdx.x * WPB;
  const int wq = lane >> 3, og = lane & 7;   // 8 words x 8 channel-octets per wave

  // initial stage: chunk 0
#pragma unroll
  for (int i = 0; i < 4; ++i) {
    const int c = tid + i * 1024;
    if (c < GROWS * 8) {
      const int row = c >> 3, cc = c & 7;
      *(f16x8*)&g_s[row * 64 + cc * 8] = *(const f16x8*)&g[row * EW_ + cc * 8];
    }
  }
  __syncthreads();

  // per-word constants, hoisted across chunks (base is chunk-invariant)
  const int wl = wave * 8 + wq;              // word 0..127
  const int* __restrict__ ipr = idx + (m0 + wl) * MW_;
  int base[MW_];
#pragma unroll
  for (int c = 0; c < MW_; ++c)
    base[c] = ipr[c] * (KW_ * 64) + og * 8;
  const int mt_a   = wl >> 4;
  const int lt_lo  = wl & 15;
  const int ks_hi  = og >> 2;
  const int lane_hi = (og & 3) << 4;
  const int lt = (lt_lo | lane_hi) ^ og;     // swizzled granule low-6

  f16x8 pre[4];
#pragma unroll
  for (int chunk = 0; chunk < 4; ++chunk) {
    const int oc0 = chunk * 64;
    // issue next chunk's loads into registers (waited only at the ds_write below)
    if (chunk < 3) {
#pragma unroll
      for (int i = 0; i < 4; ++i) {
        const int c = tid + i * 1024;
        if (c < GROWS * 8) {
          const int row = c >> 3, cc = c & 7;
          pre[i] = *(const f16x8*)&g[row * EW_ + oc0 + 64 + cc * 8];
        }
      }
    }

    f16x8 bias;
#pragma unroll
    for (int j = 0; j < 8; ++j) bias[j] = (_Float16)cb[oc0 + og * 8 + j];

    const _Float16 NEG = (_Float16)(-60000.0f);
    f16x8 mx = {NEG, NEG, NEG, NEG, NEG, NEG, NEG, NEG};
#pragma unroll
    for (int t = 0; t < T_; ++t) {
      f16x8 s = *(const f16x8*)&g_s[base[t]];              // k = 0
#pragma unroll
      for (int k = 1; k < KW_; ++k)
        s += *(const f16x8*)&g_s[base[t + k] + k * 64];    // v_pk_add_f16
      mx = __builtin_elementwise_max(mx, s);               // v_pk_max_f16
    }
    // relu(bias + max_t s) == max_t relu(bias + s)
    const f16x8 zero8 = {0, 0, 0, 0, 0, 0, 0, 0};
    mx = __builtin_elementwise_max(mx + bias, zero8);

    *(f16x8*)&y_s[((mt_a * 8 + (chunk * 2 + ks_hi)) * 64 + lt) * 8] = mx;

    __syncthreads();  // gather(c)+y-writes complete; g_s free
    if (chunk < 3) {
#pragma unroll
      for (int i = 0; i < 4; ++i) {
        const int c = tid + i * 1024;
        if (c < GROWS * 8) {
          const int row = c >> 3, cc = c & 7;
          *(f16x8*)&g_s[row * 64 + cc * 8] = pre[i];
        }
      }
      __syncthreads();
    }
  }

  // ======== phase B: dual GEMM + highway — B streamed from L2, no barriers ========
  // 16 waves: wave = (mt 0..7) x (nh 0..1); each wave: 16 rows x 128 cols.
  const int mtp = wave >> 1, nh = wave & 1;
  const int quad = lane >> 4, r16 = lane & 15;

  f16x8 a[8];
#pragma unroll
  for (int ks = 0; ks < 8; ++ks) {
    const int key = ((ks & 1) << 2) | quad;                // == writer og
    a[ks] = *(const f16x8*)&y_s[((mtp * 8 + ks) * 64 + (lane ^ key)) * 8];
  }

  const f32x4 zero = {0.f, 0.f, 0.f, 0.f};
#pragma unroll
  for (int h = 0; h < 2; ++h) {   // n-half: cols h*128 .. h*128+127
    f32x4 accp[4], accg[4];
#pragma unroll
    for (int nf = 0; nf < 4; ++nf) { accp[nf] = zero; accg[nf] = zero; }

#pragma unroll
    for (int nf = 0; nf < 4; ++nf) {
      const int nt = h * 8 + nh * 4 + nf;
#pragma unroll
      for (int ks = 0; ks < 8; ++ks) {
        const int off = ((nt * 8 + ks) * 64 + lane) * 8;
        const f16x8 bpv = *(const f16x8*)&wpf[off];
        const f16x8 bgv = *(const f16x8*)&wgf[off];
        accp[nf] = __builtin_amdgcn_mfma_f32_16x16x32_f16(a[ks], bpv, accp[nf], 0, 0, 0);
        accg[nf] = __builtin_amdgcn_mfma_f32_16x16x32_f16(a[ks], bgv, accg[nf], 0, 0, 0);
      }
    }

    // epilogue for this n-half
#pragma unroll
    for (int nf = 0; nf < 4; ++nf) {
      const int n = h * 128 + nh * 64 + nf * 16 + r16;
      const float bpn = bp[n];
      const float bgn = bg[n];
      const int ks_e = n >> 5;
      const int lane_e = ((n >> 3) & 3) << 4;
      const int og_e = (n >> 3) & 7;
      const int je = n & 7;
#pragma unroll
      for (int reg = 0; reg < 4; ++reg) {
        const int m = mtp * 16 + quad * 4 + reg;
        float p = fmaxf(accp[nf][reg] + bpn, 0.f);
        const float gz = accg[nf][reg] + bgn;
        const float gate = 1.f / (1.f + __expf(-gz));
        const float yv =
            (float)y_s[((mtp * 8 + ks_e) * 64 + (((m & 15) | lane_e) ^ og_e)) * 8 + je];
        out[(m0 + m) * EW_ + n] = gate * p + (1.f - gate) * yv;
      }
    }
  }
}

extern "C" void kernel_launch(void* const* d_in, const int* in_sizes, int n_in,
                              void* d_out, int out_size, void* d_ws, size_t ws_size,
                              hipStream_t stream) {
  (void)in_sizes; (void)n_in; (void)out_size; (void)ws_size;
  const int*   idx = (const int*)d_in[0];
  const float* emb = (const float*)d_in[1];
  const float* cw  = (const float*)d_in[2];
  const float* cb  = (const float*)d_in[3];
  const float* wp  = (const float*)d_in[4];
  const float* bpp = (const float*)d_in[5];
  const float* wgt = (const float*)d_in[6];
  const float* bgg = (const float*)d_in[7];
  float* out = (float*)d_out;
  _Float16* g_ws = (_Float16*)d_ws;            // 500*256 fp16
  _Float16* wp_f = g_ws + GROWS * EW_;         // 65536 halves, frag order
  _Float16* wg_f = wp_f + EW_ * EW_;           // 65536 halves, frag order

  k_prep<<<P1B + 32, 256, 0, stream>>>(emb, cw, wp, wgt, g_ws, wp_f, wg_f);
  k_mega<<<NW_ / WPB, 1024, 0, stream>>>(idx, g_ws, cb, wp_f, wg_f, bpp, bgg, out);
}

// Round 5
// 124.221 us; speedup vs baseline: 1.1441x; 1.0933x over previous
//
#include <hip/hip_runtime.h>

#define B_     128
#define S_     256
#define MW_    21
#define VOCAB_ 100
#define EC_    50
#define EW_    256
#define KW_    5
#define T_     17              // MW - K + 1
#define NW_    (B_ * S_)       // 32768 words
#define GROWS  (VOCAB_ * KW_)  // 500
#define WPB    128             // words per mega block
#define P1B    200             // prep part-1 blocks: 50 v-pairs x 4 o-tiles

typedef _Float16 f16x8 __attribute__((ext_vector_type(8)));
typedef float    f32x4 __attribute__((ext_vector_type(4)));

// ---------------- kernel 1: prep (unchanged from R1)
__global__ __launch_bounds__(256) void k_prep(const float* __restrict__ emb,
                                              const float* __restrict__ cw,
                                              const float* __restrict__ Wp,
                                              const float* __restrict__ Wg,
                                              _Float16* __restrict__ g,
                                              _Float16* __restrict__ wpf,
                                              _Float16* __restrict__ wgf) {
  const int bi = blockIdx.x;
  if (bi < P1B) {
    __shared__ float ls[64 * 250];          // one o-tile of cw, natural layout
    const int vp = bi >> 2, ot = bi & 3;
    const int o0 = ot * 64;
    const int tid = threadIdx.x;
    const float4* __restrict__ cw4 = (const float4*)cw + ot * 4000;  // tile base
#pragma unroll 4
    for (int idx4 = tid; idx4 < 4000; idx4 += 256)
      *(float4*)&ls[idx4 * 4] = cw4[idx4];
    __syncthreads();

    const int l = tid & 63, wv = tid >> 6;   // lane = o_local, wave = k (0..3)
#pragma unroll
    for (int vv = 0; vv < 2; ++vv) {
      const int v = vp * 2 + vv;
      const float* __restrict__ er = emb + v * EC_;   // uniform -> s_load
      float acc = 0.f;
#pragma unroll
      for (int i = 0; i < EC_; ++i)
        acc += er[i] * ls[l * 250 + i * KW_ + wv];
      g[(v * KW_ + wv) * EW_ + o0 + l] = (_Float16)acc;
      if (wv == 0) {                          // wave 0 also covers k = 4
        float a4 = 0.f;
#pragma unroll
        for (int i = 0; i < EC_; ++i)
          a4 += er[i] * ls[l * 250 + i * KW_ + 4];
        g[(v * KW_ + 4) * EW_ + o0 + l] = (_Float16)a4;
      }
    }
  } else {
    const int fl  = (bi - P1B) * 256 + threadIdx.x;  // 0..8191 lane-frags
    const int nt  = fl >> 9;
    const int rem = fl & 511;
    const int ks  = rem >> 6;
    const int l   = rem & 63;
    const int n   = nt * 16 + (l & 15);
    const int kc  = ks * 32 + (l >> 4) * 8;
    const int src = n * EW_ + kc;
    const float4 p0 = *(const float4*)&Wp[src], p1 = *(const float4*)&Wp[src + 4];
    const float4 q0 = *(const float4*)&Wg[src], q1 = *(const float4*)&Wg[src + 4];
    f16x8 hp = {(_Float16)p0.x, (_Float16)p0.y, (_Float16)p0.z, (_Float16)p0.w,
                (_Float16)p1.x, (_Float16)p1.y, (_Float16)p1.z, (_Float16)p1.w};
    f16x8 hg = {(_Float16)q0.x, (_Float16)q0.y, (_Float16)q0.z, (_Float16)q0.w,
                (_Float16)q1.x, (_Float16)q1.y, (_Float16)q1.z, (_Float16)q1.w};
    *(f16x8*)&wpf[fl * 8] = hp;
    *(f16x8*)&wgf[fl * 8] = hg;
  }
}

// ---------------- kernel 2: mega — conv+relu+maxpool (A) + dual-GEMM highway (B)
// R5: back to the PROVEN 512-thread structure (R0: 116 VGPR, no spill, 47.6us —
//   the 1024-thr variant spilled to 64 VGPR in 3/3 attempts regardless of
//   attributes; abandoned). New: PROJ-GEMM INTERLEAVED INTO THE CHUNK LOOP.
//   Each chunk produces exactly 2 of the 8 K-slices (ks=2c,2c+1) of the
//   A-fragments, so proj can accumulate per-chunk: its L2 B-frag loads (~200cy)
//   and MFMA cycles hide under the next chunk's LDS-port-bound gather (disjoint
//   pipes). Gate GEMM + epilogue stay in phase B, keeping live acc at 64 VGPR
//   (accp[2][8]) instead of 128. Phase A code is bit-identical to R0.
// g_s: plain stride-64 (GST=72 doubled conflicts in R3 — rows must stay
//   128B-aligned so each b128 phase covers every bank uniformly).
__global__ __launch_bounds__(512, 2) void k_mega(const int* __restrict__ idx,
                                                 const _Float16* __restrict__ g,
                                                 const float* __restrict__ cb,
                                                 const _Float16* __restrict__ wpf,
                                                 const _Float16* __restrict__ wgf,
                                                 const float* __restrict__ bp,
                                                 const float* __restrict__ bg,
                                                 float* __restrict__ out) {
  __shared__ __align__(16) _Float16 lds[32768 + GROWS * 64];
  _Float16* y_s = lds;            // 32768 halves: (frag*64 + (lane_t^og)) * 8 + j
  _Float16* g_s = lds + 32768;    // [500][64]

  const int tid  = threadIdx.x;
  const int wave = tid >> 6, lane = tid & 63;
  const int m0 = blockIdx.x * WPB;
  const int wq = lane >> 3, og = lane & 7;   // 8 words x 8 channel-octets per wave

  const int mtp = wave >> 1, nh = wave & 1;  // phase-B wave mapping (also proj)
  const int quad = lane >> 4, r16 = lane & 15;

  // initial stage: chunk 0
#pragma unroll
  for (int i = 0; i < 8; ++i) {
    const int c = tid + i * 512;
    if (c < GROWS * 8) {
      const int row = c >> 3, cc = c & 7;
      *(f16x8*)&g_s[row * 64 + cc * 8] = *(const f16x8*)&g[row * EW_ + cc * 8];
    }
  }
  __syncthreads();

  const f32x4 zero = {0.f, 0.f, 0.f, 0.f};
  f32x4 accp[2][8];                // proj acc: [mi][o], o = h*4+nf (all static idx)
#pragma unroll
  for (int mi = 0; mi < 2; ++mi)
#pragma unroll
    for (int o = 0; o < 8; ++o) accp[mi][o] = zero;

  f16x8 pre[8];
#pragma unroll
  for (int chunk = 0; chunk < 4; ++chunk) {
    const int oc0 = chunk * 64;
    // issue next chunk's loads into registers (waited only at the ds_write below)
    if (chunk < 3) {
#pragma unroll
      for (int i = 0; i < 8; ++i) {
        const int c = tid + i * 512;
        if (c < GROWS * 8) {
          const int row = c >> 3, cc = c & 7;
          pre[i] = *(const f16x8*)&g[row * EW_ + oc0 + 64 + cc * 8];
        }
      }
    }

    f16x8 bias;
#pragma unroll
    for (int j = 0; j < 8; ++j) bias[j] = (_Float16)cb[oc0 + og * 8 + j];

    const int ks_w    = chunk * 2 + (og >> 2);
    const int lane_hi = (og & 3) << 4;

#pragma unroll
    for (int it = 0; it < 2; ++it) {
      const int wl = it * 64 + wave * 8 + wq;
      const int* __restrict__ ip = idx + (m0 + wl) * MW_;
      int base[MW_];
#pragma unroll
      for (int c = 0; c < MW_; ++c)
        base[c] = ip[c] * (KW_ * 64) + og * 8;

      const _Float16 NEG = (_Float16)(-60000.0f);
      f16x8 mx = {NEG, NEG, NEG, NEG, NEG, NEG, NEG, NEG};
#pragma unroll
      for (int t = 0; t < T_; ++t) {
        f16x8 s = *(const f16x8*)&g_s[base[t]];              // k = 0
#pragma unroll
        for (int k = 1; k < KW_; ++k)
          s += *(const f16x8*)&g_s[base[t + k] + k * 64];    // v_pk_add_f16
        mx = __builtin_elementwise_max(mx, s);               // v_pk_max_f16
      }
      // relu(bias + max_t s) == max_t relu(bias + s)
      const f16x8 zero8 = {0, 0, 0, 0, 0, 0, 0, 0};
      mx = __builtin_elementwise_max(mx + bias, zero8);

      const int mt = wl >> 4;
      const int lt = ((wl & 15) | lane_hi) ^ og;             // swizzled granule low-6
      *(f16x8*)&y_s[((mt * 8 + ks_w) * 64 + lt) * 8] = mx;
    }
    __syncthreads();  // gather(c)+y-writes complete; g_s free
    if (chunk < 3) {
#pragma unroll
      for (int i = 0; i < 8; ++i) {
        const int c = tid + i * 512;
        if (c < GROWS * 8) {
          const int row = c >> 3, cc = c & 7;
          *(f16x8*)&g_s[row * 64 + cc * 8] = pre[i];
        }
      }
      __syncthreads();
    }

    // ---- interleaved proj-GEMM: this chunk's 2 K-slices (ks = 2c, 2c+1).
    // Reads y_s regions written before the barrier above (never rewritten);
    // L2 b-frag loads + MFMA hide under the next chunk's LDS-bound gather.
#pragma unroll
    for (int ks2 = 0; ks2 < 2; ++ks2) {
      const int ks = chunk * 2 + ks2;
      const int key = ((ks & 1) << 2) | quad;                // == writer og
      const f16x8 a0 =
          *(const f16x8*)&y_s[(((mtp * 2 + 0) * 8 + ks) * 64 + (lane ^ key)) * 8];
      const f16x8 a1 =
          *(const f16x8*)&y_s[(((mtp * 2 + 1) * 8 + ks) * 64 + (lane ^ key)) * 8];
#pragma unroll
      for (int o = 0; o < 8; ++o) {
        const int nt = (o >> 2) * 8 + nh * 4 + (o & 3);
        const f16x8 bpv = *(const f16x8*)&wpf[((nt * 8 + ks) * 64 + lane) * 8];
        accp[0][o] = __builtin_amdgcn_mfma_f32_16x16x32_f16(a0, bpv, accp[0][o], 0, 0, 0);
        accp[1][o] = __builtin_amdgcn_mfma_f32_16x16x32_f16(a1, bpv, accp[1][o], 0, 0, 0);
      }
    }
  }

  // ======== phase B: gate GEMM + highway epilogue (proj already accumulated) ====
  f16x8 a[2][8];
#pragma unroll
  for (int mi = 0; mi < 2; ++mi)
#pragma unroll
    for (int ks = 0; ks < 8; ++ks) {
      const int key = ((ks & 1) << 2) | quad;                // == writer og
      a[mi][ks] = *(const f16x8*)&y_s[(((mtp * 2 + mi) * 8 + ks) * 64 + (lane ^ key)) * 8];
    }

#pragma unroll
  for (int h = 0; h < 2; ++h) {   // n-half: cols h*128 .. h*128+127
    f32x4 accg[2][4];
#pragma unroll
    for (int mi = 0; mi < 2; ++mi)
#pragma unroll
      for (int nf = 0; nf < 4; ++nf) accg[mi][nf] = zero;

#pragma unroll
    for (int nf = 0; nf < 4; ++nf) {
      const int nt = h * 8 + nh * 4 + nf;
#pragma unroll
      for (int ks = 0; ks < 8; ++ks) {
        const int off = ((nt * 8 + ks) * 64 + lane) * 8;
        const f16x8 bgv = *(const f16x8*)&wgf[off];
#pragma unroll
        for (int mi = 0; mi < 2; ++mi)
          accg[mi][nf] = __builtin_amdgcn_mfma_f32_16x16x32_f16(a[mi][ks], bgv, accg[mi][nf], 0, 0, 0);
      }
    }

    // epilogue for this n-half
#pragma unroll
    for (int mi = 0; mi < 2; ++mi) {
      const int mt = mtp * 2 + mi;
#pragma unroll
      for (int nf = 0; nf < 4; ++nf) {
        const int n = h * 128 + nh * 64 + nf * 16 + r16;
        const float bpn = bp[n];
        const float bgn = bg[n];
        const int ks_e = n >> 5;
        const int lane_e = ((n >> 3) & 3) << 4;
        const int og_e = (n >> 3) & 7;
        const int je = n & 7;
#pragma unroll
        for (int reg = 0; reg < 4; ++reg) {
          const int m = mt * 16 + quad * 4 + reg;
          float p = fmaxf(accp[mi][h * 4 + nf][reg] + bpn, 0.f);
          const float gz = accg[mi][nf][reg] + bgn;
          const float gate = 1.f / (1.f + __expf(-gz));
          const float yv =
              (float)y_s[((mt * 8 + ks_e) * 64 + (((m & 15) | lane_e) ^ og_e)) * 8 + je];
          out[(m0 + m) * EW_ + n] = gate * p + (1.f - gate) * yv;
        }
      }
    }
  }
}

extern "C" void kernel_launch(void* const* d_in, const int* in_sizes, int n_in,
                              void* d_out, int out_size, void* d_ws, size_t ws_size,
                              hipStream_t stream) {
  (void)in_sizes; (void)n_in; (void)out_size; (void)ws_size;
  const int*   idx = (const int*)d_in[0];
  const float* emb = (const float*)d_in[1];
  const float* cw  = (const float*)d_in[2];
  const float* cb  = (const float*)d_in[3];
  const float* wp  = (const float*)d_in[4];
  const float* bpp = (const float*)d_in[5];
  const float* wgt = (const float*)d_in[6];
  const float* bgg = (const float*)d_in[7];
  float* out = (float*)d_out;
  _Float16* g_ws = (_Float16*)d_ws;            // 500*256 fp16
  _Float16* wp_f = g_ws + GROWS * EW_;         // 65536 halves, frag order
  _Float16* wg_f = wp_f + EW_ * EW_;           // 65536 halves, frag order

  k_prep<<<P1B + 32, 256, 0, stream>>>(emb, cw, wp, wgt, g_ws, wp_f, wg_f);
  k_mega<<<NW_ / WPB, 512, 0, stream>>>(idx, g_ws, cb, wp_f, wg_f, bpp, bgg, out);
}

// Round 6
// 120.344 us; speedup vs baseline: 1.1810x; 1.0322x over previous
//
#include <hip/hip_runtime.h>

#define B_     128
#define S_     256
#define MW_    21
#define VOCAB_ 100
#define EC_    50
#define EW_    256
#define KW_    5
#define T_     17              // MW - K + 1
#define NW_    (B_ * S_)       // 32768 words
#define GROWS  (VOCAB_ * KW_)  // 500
#define WPB    128             // words per mega block
#define P1B    200             // prep part-1 blocks: 50 v-pairs x 4 o-tiles

typedef _Float16 f16x8 __attribute__((ext_vector_type(8)));
typedef float    f32x4 __attribute__((ext_vector_type(4)));

// ---------------- kernel 1: prep (unchanged from R1)
__global__ __launch_bounds__(256) void k_prep(const float* __restrict__ emb,
                                              const float* __restrict__ cw,
                                              const float* __restrict__ Wp,
                                              const float* __restrict__ Wg,
                                              _Float16* __restrict__ g,
                                              _Float16* __restrict__ wpf,
                                              _Float16* __restrict__ wgf) {
  const int bi = blockIdx.x;
  if (bi < P1B) {
    __shared__ float ls[64 * 250];          // one o-tile of cw, natural layout
    const int vp = bi >> 2, ot = bi & 3;
    const int o0 = ot * 64;
    const int tid = threadIdx.x;
    const float4* __restrict__ cw4 = (const float4*)cw + ot * 4000;  // tile base
#pragma unroll 4
    for (int idx4 = tid; idx4 < 4000; idx4 += 256)
      *(float4*)&ls[idx4 * 4] = cw4[idx4];
    __syncthreads();

    const int l = tid & 63, wv = tid >> 6;   // lane = o_local, wave = k (0..3)
#pragma unroll
    for (int vv = 0; vv < 2; ++vv) {
      const int v = vp * 2 + vv;
      const float* __restrict__ er = emb + v * EC_;   // uniform -> s_load
      float acc = 0.f;
#pragma unroll
      for (int i = 0; i < EC_; ++i)
        acc += er[i] * ls[l * 250 + i * KW_ + wv];
      g[(v * KW_ + wv) * EW_ + o0 + l] = (_Float16)acc;
      if (wv == 0) {                          // wave 0 also covers k = 4
        float a4 = 0.f;
#pragma unroll
        for (int i = 0; i < EC_; ++i)
          a4 += er[i] * ls[l * 250 + i * KW_ + 4];
        g[(v * KW_ + 4) * EW_ + o0 + l] = (_Float16)a4;
      }
    }
  } else {
    const int fl  = (bi - P1B) * 256 + threadIdx.x;  // 0..8191 lane-frags
    const int nt  = fl >> 9;
    const int rem = fl & 511;
    const int ks  = rem >> 6;
    const int l   = rem & 63;
    const int n   = nt * 16 + (l & 15);
    const int kc  = ks * 32 + (l >> 4) * 8;
    const int src = n * EW_ + kc;
    const float4 p0 = *(const float4*)&Wp[src], p1 = *(const float4*)&Wp[src + 4];
    const float4 q0 = *(const float4*)&Wg[src], q1 = *(const float4*)&Wg[src + 4];
    f16x8 hp = {(_Float16)p0.x, (_Float16)p0.y, (_Float16)p0.z, (_Float16)p0.w,
                (_Float16)p1.x, (_Float16)p1.y, (_Float16)p1.z, (_Float16)p1.w};
    f16x8 hg = {(_Float16)q0.x, (_Float16)q0.y, (_Float16)q0.z, (_Float16)q0.w,
                (_Float16)q1.x, (_Float16)q1.y, (_Float16)q1.z, (_Float16)q1.w};
    *(f16x8*)&wpf[fl * 8] = hp;
    *(f16x8*)&wgf[fl * 8] = hg;
  }
}

// ---------------- kernel 2: mega — conv+relu+maxpool (A) + dual-GEMM highway (B)
// R6: phase A = bit-exact R0 (proven 47.6us; R5's interleave lost 2.4us —
//   barrier-lockstep makes all waves MFMA together then gather together, no
//   overlap). Phase B RETILED for L2 bandwidth: it streamed 1 MB/block of
//   B-fragments (each frag re-read by the 4 waves sharing its nh) ~ 7.6us at
//   135 GB/s/CU of L2. New tiling: wave = (mtp2 0..1) x (nq 0..3), 4 m-tiles
//   per wave -> each B-frag read by 2 waves instead of 4 -> 512 KB/block
//   (~3.8us). Same MFMA count, same ks-ascending accumulation order (bitwise-
//   identical numerics). Cost: accp+accg = 128 acc VGPRs live (~170-200 total,
//   fits the (512,2) 256-VGPR budget; R5 showed the 512-thr heuristic follows
//   need without spilling).
// g_s: plain stride-64 (R3: padding doubled conflicts; rows must stay
//   128B-aligned so each b128 phase covers every bank uniformly).
__global__ __launch_bounds__(512, 2) void k_mega(const int* __restrict__ idx,
                                                 const _Float16* __restrict__ g,
                                                 const float* __restrict__ cb,
                                                 const _Float16* __restrict__ wpf,
                                                 const _Float16* __restrict__ wgf,
                                                 const float* __restrict__ bp,
                                                 const float* __restrict__ bg,
                                                 float* __restrict__ out) {
  __shared__ __align__(16) _Float16 lds[32768 + GROWS * 64];
  _Float16* y_s = lds;            // 32768 halves: (frag*64 + (lane_t^og)) * 8 + j
  _Float16* g_s = lds + 32768;    // [500][64]

  const int tid  = threadIdx.x;
  const int wave = tid >> 6, lane = tid & 63;
  const int m0 = blockIdx.x * WPB;
  const int wq = lane >> 3, og = lane & 7;   // 8 words x 8 channel-octets per wave

  // initial stage: chunk 0
#pragma unroll
  for (int i = 0; i < 8; ++i) {
    const int c = tid + i * 512;
    if (c < GROWS * 8) {
      const int row = c >> 3, cc = c & 7;
      *(f16x8*)&g_s[row * 64 + cc * 8] = *(const f16x8*)&g[row * EW_ + cc * 8];
    }
  }
  __syncthreads();

  f16x8 pre[8];
#pragma unroll
  for (int chunk = 0; chunk < 4; ++chunk) {
    const int oc0 = chunk * 64;
    // issue next chunk's loads into registers (waited only at the ds_write below)
    if (chunk < 3) {
#pragma unroll
      for (int i = 0; i < 8; ++i) {
        const int c = tid + i * 512;
        if (c < GROWS * 8) {
          const int row = c >> 3, cc = c & 7;
          pre[i] = *(const f16x8*)&g[row * EW_ + oc0 + 64 + cc * 8];
        }
      }
    }

    f16x8 bias;
#pragma unroll
    for (int j = 0; j < 8; ++j) bias[j] = (_Float16)cb[oc0 + og * 8 + j];

    const int ks_w    = chunk * 2 + (og >> 2);
    const int lane_hi = (og & 3) << 4;

#pragma unroll
    for (int it = 0; it < 2; ++it) {
      const int wl = it * 64 + wave * 8 + wq;
      const int* __restrict__ ip = idx + (m0 + wl) * MW_;
      int base[MW_];
#pragma unroll
      for (int c = 0; c < MW_; ++c)
        base[c] = ip[c] * (KW_ * 64) + og * 8;

      const _Float16 NEG = (_Float16)(-60000.0f);
      f16x8 mx = {NEG, NEG, NEG, NEG, NEG, NEG, NEG, NEG};
#pragma unroll
      for (int t = 0; t < T_; ++t) {
        f16x8 s = *(const f16x8*)&g_s[base[t]];              // k = 0
#pragma unroll
        for (int k = 1; k < KW_; ++k)
          s += *(const f16x8*)&g_s[base[t + k] + k * 64];    // v_pk_add_f16
        mx = __builtin_elementwise_max(mx, s);               // v_pk_max_f16
      }
      // relu(bias + max_t s) == max_t relu(bias + s)
      const f16x8 zero8 = {0, 0, 0, 0, 0, 0, 0, 0};
      mx = __builtin_elementwise_max(mx + bias, zero8);

      const int mt = wl >> 4;
      const int lt = ((wl & 15) | lane_hi) ^ og;             // swizzled granule low-6
      *(f16x8*)&y_s[((mt * 8 + ks_w) * 64 + lt) * 8] = mx;
    }
    __syncthreads();  // gather(c)+y-writes complete; g_s free
    if (chunk < 3) {
#pragma unroll
      for (int i = 0; i < 8; ++i) {
        const int c = tid + i * 512;
        if (c < GROWS * 8) {
          const int row = c >> 3, cc = c & 7;
          *(f16x8*)&g_s[row * 64 + cc * 8] = pre[i];
        }
      }
      __syncthreads();
    }
  }

  // ======== phase B: dual GEMM + highway — retiled 4m x 4nt per wave ========
  const int mtp2 = wave >> 2, nq = wave & 3;   // 2 m-groups x 4 n-quarters
  const int quad = lane >> 4, r16 = lane & 15;

  const f32x4 zero = {0.f, 0.f, 0.f, 0.f};
  f32x4 accp[4][4], accg[4][4];
#pragma unroll
  for (int mi = 0; mi < 4; ++mi)
#pragma unroll
    for (int nf = 0; nf < 4; ++nf) { accp[mi][nf] = zero; accg[mi][nf] = zero; }

#pragma unroll
  for (int ks = 0; ks < 8; ++ks) {
    const int key = ((ks & 1) << 2) | quad;                  // == writer og
    f16x8 a[4];
#pragma unroll
    for (int mi = 0; mi < 4; ++mi)
      a[mi] = *(const f16x8*)&y_s[(((mtp2 * 4 + mi) * 8 + ks) * 64 + (lane ^ key)) * 8];
#pragma unroll
    for (int nf = 0; nf < 4; ++nf) {
      const int nt = nq * 4 + nf;
      const int off = ((nt * 8 + ks) * 64 + lane) * 8;
      const f16x8 bpv = *(const f16x8*)&wpf[off];
      const f16x8 bgv = *(const f16x8*)&wgf[off];
#pragma unroll
      for (int mi = 0; mi < 4; ++mi) {
        accp[mi][nf] = __builtin_amdgcn_mfma_f32_16x16x32_f16(a[mi], bpv, accp[mi][nf], 0, 0, 0);
        accg[mi][nf] = __builtin_amdgcn_mfma_f32_16x16x32_f16(a[mi], bgv, accg[mi][nf], 0, 0, 0);
      }
    }
  }

  // epilogue
#pragma unroll
  for (int mi = 0; mi < 4; ++mi) {
    const int mt = mtp2 * 4 + mi;
#pragma unroll
    for (int nf = 0; nf < 4; ++nf) {
      const int n = nq * 64 + nf * 16 + r16;
      const float bpn = bp[n];
      const float bgn = bg[n];
      const int ks_e = n >> 5;
      const int lane_e = ((n >> 3) & 3) << 4;
      const int og_e = (n >> 3) & 7;
      const int je = n & 7;
#pragma unroll
      for (int reg = 0; reg < 4; ++reg) {
        const int m = mt * 16 + quad * 4 + reg;
        float p = fmaxf(accp[mi][nf][reg] + bpn, 0.f);
        const float gz = accg[mi][nf][reg] + bgn;
        const float gate = 1.f / (1.f + __expf(-gz));
        const float yv =
            (float)y_s[((mt * 8 + ks_e) * 64 + (((m & 15) | lane_e) ^ og_e)) * 8 + je];
        out[(m0 + m) * EW_ + n] = gate * p + (1.f - gate) * yv;
      }
    }
  }
}

extern "C" void kernel_launch(void* const* d_in, const int* in_sizes, int n_in,
                              void* d_out, int out_size, void* d_ws, size_t ws_size,
                              hipStream_t stream) {
  (void)in_sizes; (void)n_in; (void)out_size; (void)ws_size;
  const int*   idx = (const int*)d_in[0];
  const float* emb = (const float*)d_in[1];
  const float* cw  = (const float*)d_in[2];
  const float* cb  = (const float*)d_in[3];
  const float* wp  = (const float*)d_in[4];
  const float* bpp = (const float*)d_in[5];
  const float* wgt = (const float*)d_in[6];
  const float* bgg = (const float*)d_in[7];
  float* out = (float*)d_out;
  _Float16* g_ws = (_Float16*)d_ws;            // 500*256 fp16
  _Float16* wp_f = g_ws + GROWS * EW_;         // 65536 halves, frag order
  _Float16* wg_f = wp_f + EW_ * EW_;           // 65536 halves, frag order

  k_prep<<<P1B + 32, 256, 0, stream>>>(emb, cw, wp, wgt, g_ws, wp_f, wg_f);
  k_mega<<<NW_ / WPB, 512, 0, stream>>>(idx, g_ws, cb, wp_f, wg_f, bpp, bgg, out);
}